// Round 2
// baseline (99.276 us; speedup 1.0000x reference)
//
#include <hip/hip_runtime.h>

typedef __attribute__((ext_vector_type(8))) _Float16 f16x8;
typedef __attribute__((ext_vector_type(4))) _Float16 f16x4;
typedef __attribute__((ext_vector_type(4))) float   f32x4;

#define BATCH 16384
#define NFEAT 512
#define NCLS  1000
#define NLEAF 256
#define NINT  255
#define NPAD  1024
#define LDP   72   // padded LDS row stride (f16) : 144B -> 2-way bank alias (free)

// ---- convert gate_w (255x512) -> f16 padded to 256x512 (row 255 = 0) ----
__global__ __launch_bounds__(256) void cvt_gw(const float4* __restrict__ in,
                                              f16x4* __restrict__ out) {
  int i = blockIdx.x * 256 + threadIdx.x;   // quad index, 32768 total
  int row = i >> 7;                          // 128 quads per row
  f16x4 o;
  if (row < NINT) {
    float4 v = in[i];
    o[0] = (_Float16)v.x; o[1] = (_Float16)v.y;
    o[2] = (_Float16)v.z; o[3] = (_Float16)v.w;
  } else {
    o[0] = o[1] = o[2] = o[3] = (_Float16)0.f;
  }
  out[i] = o;
}

// ---- softmax rows of leaf_logits (256x1000) -> distT[c][l] f16, rows 1000..1023 zeroed ----
__global__ __launch_bounds__(256) void softmax_t(const float* __restrict__ L,
                                                 _Float16* __restrict__ distT) {
  __shared__ float red[256];
  int l = blockIdx.x, t = threadIdx.x;
  float v[4];
  float mx = -1e30f;
#pragma unroll
  for (int i = 0; i < 4; ++i) {
    int c = t + i * 256;
    if (c < NCLS) { v[i] = L[l * NCLS + c]; mx = fmaxf(mx, v[i]); }
    else v[i] = -1e30f;
  }
  red[t] = mx; __syncthreads();
  for (int s = 128; s > 0; s >>= 1) {
    if (t < s) red[t] = fmaxf(red[t], red[t + s]);
    __syncthreads();
  }
  mx = red[0]; __syncthreads();
  float e[4], sum = 0.f;
#pragma unroll
  for (int i = 0; i < 4; ++i) {
    int c = t + i * 256;
    if (c < NCLS) { e[i] = expf(v[i] - mx); sum += e[i]; } else e[i] = 0.f;
  }
  red[t] = sum; __syncthreads();
  for (int s = 128; s > 0; s >>= 1) {
    if (t < s) red[t] += red[t + s];
    __syncthreads();
  }
  float inv = 1.f / red[0];
#pragma unroll
  for (int i = 0; i < 4; ++i) {
    int c = t + i * 256;
    if (c < NCLS) distT[(size_t)c * NLEAF + l] = (_Float16)(e[i] * inv);
  }
  if (t < NPAD - NCLS) distT[(size_t)(NCLS + t) * NLEAF + l] = (_Float16)0.f;
}

// ---- fused: gates = sigmoid(x @ gwh^T + b); mu = tree-product -> f16 ----
// BM=64 rows/block, BN=256 (all nodes), K=512, BK=64. 512 threads = 8 waves (2x4).
__global__ __launch_bounds__(512)
void gate_mu(const float* __restrict__ x, const _Float16* __restrict__ gwh,
             const float* __restrict__ gb, _Float16* __restrict__ mu) {
  __shared__ union {
    struct { _Float16 A[64 * LDP]; _Float16 B[256 * LDP]; } s;
    float P[64 * 256];
  } sm;
  const int tid = threadIdx.x;
  const int wave = tid >> 6, lane = tid & 63;
  const int ln15 = lane & 15, lhi = lane >> 4;
  const int wr = wave >> 2, wc = wave & 3;          // 2 x 4 waves, 32r x 64c each
  const int r0 = blockIdx.x * 64;

  f32x4 acc[2][4] = {};

  // staging index maps (fixed per thread)
  const int arow = tid >> 4, acol = (tid & 15) * 4;        // A: 64 rows x 16 float4
  const int brow0 = tid >> 3, bcol = (tid & 7) * 8;        // B: per iter 64 rows x 8 chunks

  float4 pa;        // A prefetch: 1 float4/thread/K-step (64*64 f32 = 512thr*2... see below)
  float4 pa2;
  uint4  pb[4];

  // A tile 64x64 f32 = 4096 f32 = 1024 float4 -> 2 per thread
  // B tile 256x64 f16 = 2048 16B chunks -> 4 per thread
#define LOAD_AB(k0)                                                        \
  {                                                                        \
    pa  = *(const float4*)&x[(size_t)(r0 + arow) * NFEAT + (k0) + acol];   \
    pa2 = *(const float4*)&x[(size_t)(r0 + 32 + arow) * NFEAT + (k0) + acol]; \
    _Pragma("unroll")                                                      \
    for (int i = 0; i < 4; ++i)                                            \
      pb[i] = *(const uint4*)&gwh[(size_t)(i * 64 + brow0) * NFEAT + (k0) + bcol]; \
  }
#define WRITE_AB()                                                         \
  {                                                                        \
    f16x4 h;                                                               \
    h[0] = (_Float16)pa.x; h[1] = (_Float16)pa.y;                          \
    h[2] = (_Float16)pa.z; h[3] = (_Float16)pa.w;                          \
    *(f16x4*)&sm.s.A[arow * LDP + acol] = h;                               \
    h[0] = (_Float16)pa2.x; h[1] = (_Float16)pa2.y;                        \
    h[2] = (_Float16)pa2.z; h[3] = (_Float16)pa2.w;                        \
    *(f16x4*)&sm.s.A[(32 + arow) * LDP + acol] = h;                        \
    _Pragma("unroll")                                                      \
    for (int i = 0; i < 4; ++i)                                            \
      *(uint4*)&sm.s.B[(i * 64 + brow0) * LDP + bcol] = pb[i];             \
  }

  // wait: arow covers 0..31 only (tid>>4 max 31)? 512 threads -> tid>>4 in 0..31.
  // So pa covers rows 0..31, pa2 rows 32..63. Correct.

  LOAD_AB(0);
  WRITE_AB();
  __syncthreads();

  for (int k = 0; k < NFEAT / 64; ++k) {
    if (k < NFEAT / 64 - 1) LOAD_AB((k + 1) * 64);
#pragma unroll
    for (int kk = 0; kk < 2; ++kk) {
      f16x8 a[2], b[4];
#pragma unroll
      for (int m = 0; m < 2; ++m)
        a[m] = *(const f16x8*)&sm.s.A[(wr * 32 + m * 16 + ln15) * LDP + kk * 32 + lhi * 8];
#pragma unroll
      for (int n = 0; n < 4; ++n)
        b[n] = *(const f16x8*)&sm.s.B[(wc * 64 + n * 16 + ln15) * LDP + kk * 32 + lhi * 8];
#pragma unroll
      for (int m = 0; m < 2; ++m)
#pragma unroll
        for (int n = 0; n < 4; ++n)
          acc[m][n] = __builtin_amdgcn_mfma_f32_16x16x32_f16(a[m], b[n], acc[m][n], 0, 0, 0);
    }
    __syncthreads();
    if (k < NFEAT / 64 - 1) { WRITE_AB(); __syncthreads(); }
  }

  // epilogue 1: sigmoid -> P in LDS (row-local x node)
#pragma unroll
  for (int m = 0; m < 2; ++m)
#pragma unroll
    for (int n = 0; n < 4; ++n) {
      int col = wc * 64 + n * 16 + ln15;
      float bb = (col < NINT) ? gb[col] : 0.f;
#pragma unroll
      for (int j = 0; j < 4; ++j) {
        int rl = wr * 32 + m * 16 + lhi * 4 + j;
        float v = acc[m][n][j] + bb;
        sm.P[rl * 256 + col] = 1.f / (1.f + __expf(-v));
      }
    }
  __syncthreads();

  // epilogue 2: tree product. wave handles 8 rows; lane handles leaves 4*lane..4*lane+3
  const int lf = lane * 4;
#pragma unroll
  for (int rr = 0; rr < 8; ++rr) {
    int row = wave * 8 + rr;
    const float* p = &sm.P[row * 256];
    float pre = 1.f;
#pragma unroll
    for (int d = 0; d < 6; ++d) {
      int node = (1 << d) - 1 + (lf >> (8 - d));
      int bit  = (lf >> (7 - d)) & 1;
      float g = p[node];
      pre *= bit ? g : (1.f - g);
    }
    float g6  = p[63 + lane];
    float g7a = p[127 + 2 * lane];
    float g7b = p[128 + 2 * lane];
    f16x4 o;
    o[0] = (_Float16)(pre * (1.f - g6) * (1.f - g7a));
    o[1] = (_Float16)(pre * (1.f - g6) * g7a);
    o[2] = (_Float16)(pre * g6 * (1.f - g7b));
    o[3] = (_Float16)(pre * g6 * g7b);
    *(f16x4*)&mu[(size_t)(r0 + row) * 256 + lf] = o;
  }
#undef LOAD_AB
#undef WRITE_AB
}

// ---- gemm2: out = mu(16384x256) @ distT(1024x256)^T, 128x128 tile, BK=64, padded LDS ----
__global__ __launch_bounds__(256)
void gemm2(const _Float16* __restrict__ A, const _Float16* __restrict__ B,
           float* __restrict__ out) {
  __shared__ _Float16 lA[128 * LDP];
  __shared__ _Float16 lB[128 * LDP];
  const int tid = threadIdx.x;
  const int wave = tid >> 6, lane = tid & 63;
  const int ln15 = lane & 15, lhi = lane >> 4;
  const int wr = wave >> 1, wc = wave & 1;          // 2x2 waves, 64r x 64c each
  const int r0 = blockIdx.x * 128;
  const int c0 = blockIdx.y * 128;

  f32x4 acc[4][4] = {};

  const int srow = tid >> 3, scol = (tid & 7) * 8;  // per iter: 32 rows x 8 chunks
  uint4 pa[4], pb[4];

#define G2_LOAD(k0)                                                         \
  {                                                                         \
    _Pragma("unroll")                                                       \
    for (int i = 0; i < 4; ++i) {                                           \
      pa[i] = *(const uint4*)&A[(size_t)(r0 + i * 32 + srow) * 256 + (k0) + scol]; \
      pb[i] = *(const uint4*)&B[(size_t)(c0 + i * 32 + srow) * 256 + (k0) + scol]; \
    }                                                                       \
  }
#define G2_WRITE()                                                          \
  {                                                                         \
    _Pragma("unroll")                                                       \
    for (int i = 0; i < 4; ++i) {                                           \
      *(uint4*)&lA[(i * 32 + srow) * LDP + scol] = pa[i];                   \
      *(uint4*)&lB[(i * 32 + srow) * LDP + scol] = pb[i];                   \
    }                                                                       \
  }

  G2_LOAD(0);
  G2_WRITE();
  __syncthreads();

  for (int k = 0; k < 4; ++k) {
    if (k < 3) G2_LOAD((k + 1) * 64);
#pragma unroll
    for (int kk = 0; kk < 2; ++kk) {
      f16x8 a[4], b[4];
#pragma unroll
      for (int m = 0; m < 4; ++m)
        a[m] = *(const f16x8*)&lA[(wr * 64 + m * 16 + ln15) * LDP + kk * 32 + lhi * 8];
#pragma unroll
      for (int n = 0; n < 4; ++n)
        b[n] = *(const f16x8*)&lB[(wc * 64 + n * 16 + ln15) * LDP + kk * 32 + lhi * 8];
#pragma unroll
      for (int m = 0; m < 4; ++m)
#pragma unroll
        for (int n = 0; n < 4; ++n)
          acc[m][n] = __builtin_amdgcn_mfma_f32_16x16x32_f16(a[m], b[n], acc[m][n], 0, 0, 0);
    }
    __syncthreads();
    if (k < 3) { G2_WRITE(); __syncthreads(); }
  }

#pragma unroll
  for (int m = 0; m < 4; ++m)
#pragma unroll
    for (int n = 0; n < 4; ++n) {
      int col = c0 + wc * 64 + n * 16 + ln15;
      if (col < NCLS) {
#pragma unroll
        for (int j = 0; j < 4; ++j) {
          int row = r0 + wr * 64 + m * 16 + lhi * 4 + j;
          out[(size_t)row * NCLS + col] = acc[m][n][j];
        }
      }
    }
#undef G2_LOAD
#undef G2_WRITE
}

extern "C" void kernel_launch(void* const* d_in, const int* in_sizes, int n_in,
                              void* d_out, int out_size, void* d_ws, size_t ws_size,
                              hipStream_t stream) {
  const float* x  = (const float*)d_in[0];   // 16384x512
  const float* gw = (const float*)d_in[1];   // 255x512
  const float* gb = (const float*)d_in[2];   // 255
  const float* ll = (const float*)d_in[3];   // 256x1000
  float* out = (float*)d_out;                // 16384x1000
  char* ws = (char*)d_ws;

  _Float16* gwh   = (_Float16*)(ws);                 // 262,144 B
  _Float16* distT = (_Float16*)(ws + 262144);        // 524,288 B
  _Float16* mu    = (_Float16*)(ws + 786432);        // 8,388,608 B

  cvt_gw   <<<128, 256, 0, stream>>>((const float4*)gw, (f16x4*)gwh);
  softmax_t<<<256, 256, 0, stream>>>(ll, distT);
  gate_mu  <<<BATCH / 64, 512, 0, stream>>>(x, gwh, gb, mu);
  gemm2    <<<dim3(BATCH / 128, NPAD / 128), 256, 0, stream>>>(mu, distT, out);
}